// Round 4
// baseline (647.592 us; speedup 1.0000x reference)
//
#include <hip/hip_runtime.h>
#include <hip/hip_bf16.h>

#define N_NODES 100000
#define N_TYPES 10
#define N_EDGES 3200000
#define HIDDEN 256
#define EMBED 128
#define N_PAIRS 100000

typedef _Float16 half2v __attribute__((ext_vector_type(2)));
typedef _Float16 half4v __attribute__((ext_vector_type(4)));
typedef _Float16 half8v __attribute__((ext_vector_type(8)));
typedef float floatx4 __attribute__((ext_vector_type(4)));

#define GLOBAL_AS __attribute__((address_space(1)))
#define LDS_AS __attribute__((address_space(3)))

static __device__ __forceinline__ void async_copy16(const void* g, void* lds) {
    __builtin_amdgcn_global_load_lds((const GLOBAL_AS unsigned int*)g,
                                     (LDS_AS unsigned int*)(void*)lds, 16, 0, 0);
}

// ---------------------------------------------------------------------------
// row_ptr from sorted rows (binary search, no atomics)
// ---------------------------------------------------------------------------
__global__ void build_rowptr_k(const int* __restrict__ rows, int* __restrict__ rp,
                               int n_nodes, int n_edges) {
    int n = blockIdx.x * blockDim.x + threadIdx.x;
    if (n > n_nodes) return;
    int lo = 0, hi = n_edges;
    while (lo < hi) {
        int mid = (lo + hi) >> 1;
        if (rows[mid] < n) lo = mid + 1; else hi = mid;
    }
    rp[n] = lo;
}

// ---------------------------------------------------------------------------
// x halves: xa[n][0:128], xb[n][0:128] = fp16(node_emb[n][f] + type_emb[t][f])
// ---------------------------------------------------------------------------
__global__ void build_x16_k(const float* __restrict__ node_emb,
                            const float* __restrict__ type_emb,
                            const int* __restrict__ ntype,
                            _Float16* __restrict__ xa, _Float16* __restrict__ xb) {
    int idx = blockIdx.x * blockDim.x + threadIdx.x;
    int n  = idx >> 6;
    if (n >= N_NODES) return;
    int f4 = (idx & 63) * 4;
    int t = ntype[n];
    float4 a = *(const float4*)&node_emb[(size_t)n * HIDDEN + f4];
    float4 b = *(const float4*)&type_emb[(size_t)t * HIDDEN + f4];
    half4v o;
    o.x = (_Float16)(a.x + b.x);
    o.y = (_Float16)(a.y + b.y);
    o.z = (_Float16)(a.z + b.z);
    o.w = (_Float16)(a.w + b.w);
    if (f4 < 128)
        *(half4v*)&xa[(size_t)n * 128 + f4] = o;
    else
        *(half4v*)&xb[(size_t)n * 128 + (f4 - 128)] = o;
}

// ---------------------------------------------------------------------------
// Wt[n][k] = fp16(W[k][n])  for K=256 weights (W1, W2)
// ---------------------------------------------------------------------------
__global__ void transpose_w_k(const float* __restrict__ W, _Float16* __restrict__ Wt,
                              int K, int N) {
    int idx = blockIdx.x * blockDim.x + threadIdx.x;
    if (idx >= K * N) return;
    int k = idx & 255;
    int n = idx >> 8;
    Wt[idx] = (_Float16)W[(size_t)k * N + n];
}

// Wp1 [384,128] -> Wp1t [128][384] fp16
__global__ void transpose_wp1_k(const float* __restrict__ W, _Float16* __restrict__ Wt) {
    int k = threadIdx.x;
    int n = blockIdx.x;
    Wt[n * 384 + k] = (_Float16)W[(size_t)k * EMBED + n];
}

// ---------------------------------------------------------------------------
// 128-wide spmm pass: out[n*out_stride + out_off + f] =
//     fp16( sum_e val[e] * table[cols[e]][f] (+ bias[f]) )
// table: [N,128] fp16. one wave/node, lane = 2 feats. edge list scalarized.
// ---------------------------------------------------------------------------
template <bool BIAS>
__global__ void spmm128_k(const int* __restrict__ rp, const int* __restrict__ cols,
                          const float* __restrict__ vals,
                          const _Float16* __restrict__ table,
                          const float* __restrict__ bias,
                          _Float16* __restrict__ out, int out_stride, int out_off) {
    int wave = threadIdx.x >> 6, lane = threadIdx.x & 63;
    int n = blockIdx.x * 4 + wave;
    int e0 = __builtin_amdgcn_readfirstlane(rp[n]);
    int e1 = __builtin_amdgcn_readfirstlane(rp[n + 1]);
    int fo = lane * 2;
    float ax = 0.f, ay = 0.f;
    int e = e0;
    for (; e + 16 <= e1; e += 16) {
        int c[16]; float v[16];
#pragma unroll
        for (int i = 0; i < 16; ++i) { c[i] = cols[e + i]; v[i] = vals[e + i]; }
        half2v h[16];
#pragma unroll
        for (int i = 0; i < 16; ++i)
            h[i] = *(const half2v*)&table[(size_t)c[i] * 128 + fo];
#pragma unroll
        for (int i = 0; i < 16; ++i) {
            ax += v[i] * (float)h[i].x;
            ay += v[i] * (float)h[i].y;
        }
    }
    for (; e < e1; ++e) {
        int c0 = cols[e]; float v0 = vals[e];
        half2v h0 = *(const half2v*)&table[(size_t)c0 * 128 + fo];
        ax += v0 * (float)h0.x;
        ay += v0 * (float)h0.y;
    }
    if (BIAS) { ax += bias[fo]; ay += bias[fo + 1]; }
    half2v o;
    o.x = (_Float16)ax; o.y = (_Float16)ay;
    *(half2v*)&out[(size_t)n * out_stride + out_off + fo] = o;
}

// ---------------------------------------------------------------------------
// fp16 MFMA GEMM: C16 = [relu](A @ Bt^T + bias), A [M,256], Bt [N,256]
// 128x128 tile, BK=32, 256 thr, global_load_lds width-16 staging
// ---------------------------------------------------------------------------
template <bool RELU, bool BIAS>
__global__ void gemm16_k(const _Float16* __restrict__ A,
                         const _Float16* __restrict__ Bt,
                         const float* __restrict__ bias,
                         _Float16* __restrict__ C,
                         int M, int N) {
    const int K = 256;
    __shared__ _Float16 As[128 * 32];
    __shared__ _Float16 Bs[128 * 32];

    int t = threadIdx.x;
    int lane = t & 63;
    int wave = t >> 6;
    int quad = lane >> 4;
    int m16 = lane & 15;
    int wr = wave >> 1, wc = wave & 1;
    int m0 = blockIdx.x * 128;
    int n0 = blockIdx.y * 128;

    int srow = t >> 2;
    int skoff = (t & 3) * 8;

    floatx4 acc[4][4];
#pragma unroll
    for (int i = 0; i < 4; ++i)
#pragma unroll
        for (int j = 0; j < 4; ++j)
            acc[i][j] = (floatx4)0.f;

    for (int k0 = 0; k0 < K; k0 += 32) {
        int ra0 = m0 + srow;       if (ra0 >= M) ra0 = M - 1;
        int ra1 = m0 + srow + 64;  if (ra1 >= M) ra1 = M - 1;
        async_copy16(&A[(size_t)ra0 * K + k0 + skoff], &As[srow * 32 + skoff]);
        async_copy16(&A[(size_t)ra1 * K + k0 + skoff], &As[(srow + 64) * 32 + skoff]);
        async_copy16(&Bt[(size_t)(n0 + srow) * K + k0 + skoff], &Bs[srow * 32 + skoff]);
        async_copy16(&Bt[(size_t)(n0 + srow + 64) * K + k0 + skoff], &Bs[(srow + 64) * 32 + skoff]);
        __syncthreads();

        half8v aF[4], bF[4];
#pragma unroll
        for (int i = 0; i < 4; ++i)
            aF[i] = *(const half8v*)&As[(wr * 64 + i * 16 + m16) * 32 + quad * 8];
#pragma unroll
        for (int j = 0; j < 4; ++j)
            bF[j] = *(const half8v*)&Bs[(wc * 64 + j * 16 + m16) * 32 + quad * 8];
#pragma unroll
        for (int i = 0; i < 4; ++i)
#pragma unroll
            for (int j = 0; j < 4; ++j)
                acc[i][j] = __builtin_amdgcn_mfma_f32_16x16x32_f16(aF[i], bF[j], acc[i][j], 0, 0, 0);
        __syncthreads();
    }

#pragma unroll
    for (int i = 0; i < 4; ++i) {
#pragma unroll
        for (int j = 0; j < 4; ++j) {
            int gr = m0 + wr * 64 + i * 16 + quad * 4;
            int gc = n0 + wc * 64 + j * 16 + m16;
            float bv = BIAS ? bias[gc] : 0.f;
#pragma unroll
            for (int r = 0; r < 4; ++r) {
                int row = gr + r;
                if (row < M) {
                    float v = acc[i][j][r] + bv;
                    if (RELU) v = v > 0.f ? v : 0.f;
                    C[(size_t)row * N + gc] = (_Float16)v;
                }
            }
        }
    }
}

// ---------------------------------------------------------------------------
// MFMA fp16 pair scorer: 128 pairs/block, K=384 in 3 regions of 128.
// Fs (features) staged in LDS; Wp1t fragments read directly from global
// (96 KB, shared by all blocks -> L2-hot). LDS ~35 KB -> 4 blocks/CU.
// ---------------------------------------------------------------------------
__global__ __launch_bounds__(256) void scorer_mfma_k(
        const _Float16* __restrict__ z16, const int* __restrict__ pairs,
        const _Float16* __restrict__ Wp1t, const float* __restrict__ bp1,
        const float* __restrict__ Wp2, const float* __restrict__ bp2,
        float* __restrict__ out, int P) {
    __shared__ _Float16 Fs[128][136];   // feat chunk [pair][k], +8 pad
    __shared__ int sidx[128], didx[128];
    __shared__ float red[128][2];

    int t  = threadIdx.x;
    int p0 = blockIdx.x * 128;

    if (t < 128) {
        int p = p0 + t;
        if (p >= P) p = P - 1;
        sidx[t] = pairs[p];
        didx[t] = pairs[P + p];
    }
    __syncthreads();

    int lane = t & 63, wave = t >> 6;
    int quad = lane >> 4, m16 = lane & 15;
    int wr = wave >> 1, wc = wave & 1;

    floatx4 acc[4][4];
#pragma unroll
    for (int i = 0; i < 4; ++i)
#pragma unroll
        for (int j = 0; j < 4; ++j)
            acc[i][j] = (floatx4)0.f;

    int pr = t & 127;          // staging row (pair)
    int kh = (t >> 7) * 64;    // k-half offset 0 / 64

    for (int r = 0; r < 3; ++r) {
        // stage feat region into LDS
        {
            const _Float16* zs = &z16[(size_t)sidx[pr] * EMBED + kh];
            const _Float16* zd = &z16[(size_t)didx[pr] * EMBED + kh];
            half8v f[8];
            if (r == 0) {
#pragma unroll
                for (int i = 0; i < 8; ++i) f[i] = *(const half8v*)&zs[i * 8];
            } else if (r == 1) {
#pragma unroll
                for (int i = 0; i < 8; ++i) f[i] = *(const half8v*)&zd[i * 8];
            } else {
#pragma unroll
                for (int i = 0; i < 8; ++i) {
                    half8v a = *(const half8v*)&zs[i * 8];
                    half8v b = *(const half8v*)&zd[i * 8];
                    f[i] = a * b;
                }
            }
#pragma unroll
            for (int i = 0; i < 8; ++i)
                *(half8v*)&Fs[pr][kh + i * 8] = f[i];
        }
        __syncthreads();

#pragma unroll
        for (int k0 = 0; k0 < 128; k0 += 32) {
            half8v aF[4], bF[4];
#pragma unroll
            for (int i = 0; i < 4; ++i)
                aF[i] = *(const half8v*)&Fs[wr * 64 + i * 16 + m16][k0 + quad * 8];
#pragma unroll
            for (int j = 0; j < 4; ++j)
                bF[j] = *(const half8v*)&Wp1t[(size_t)(wc * 64 + j * 16 + m16) * 384
                                              + r * 128 + k0 + quad * 8];
#pragma unroll
            for (int i = 0; i < 4; ++i)
#pragma unroll
                for (int j = 0; j < 4; ++j)
                    acc[i][j] = __builtin_amdgcn_mfma_f32_16x16x32_f16(aF[i], bF[j], acc[i][j], 0, 0, 0);
        }
        __syncthreads();
    }

    // epilogue: relu(acc + bp1) . Wp2, shfl-reduce across the 16 col lanes
    float w2v[4], b1v[4];
#pragma unroll
    for (int j = 0; j < 4; ++j) {
        int col = wc * 64 + j * 16 + m16;
        w2v[j] = Wp2[col];
        b1v[j] = bp1[col];
    }
#pragma unroll
    for (int i = 0; i < 4; ++i) {
#pragma unroll
        for (int rr = 0; rr < 4; ++rr) {
            float partial = 0.f;
#pragma unroll
            for (int j = 0; j < 4; ++j) {
                float v = acc[i][j][rr] + b1v[j];
                v = v > 0.f ? v : 0.f;
                partial += v * w2v[j];
            }
#pragma unroll
            for (int off = 1; off < 16; off <<= 1)
                partial += __shfl_xor(partial, off, 64);
            if (m16 == 0)
                red[wr * 64 + i * 16 + quad * 4 + rr][wc] = partial;
        }
    }
    __syncthreads();
    if (t < 128) {
        int p = p0 + t;
        if (p < P) out[p] = red[t][0] + red[t][1] + bp2[0];
    }
}

// ---------------------------------------------------------------------------
// Launch
// ---------------------------------------------------------------------------
extern "C" void kernel_launch(void* const* d_in, const int* in_sizes, int n_in,
                              void* d_out, int out_size, void* d_ws, size_t ws_size,
                              hipStream_t stream) {
    const int*   node_type_ids = (const int*)d_in[0];
    const int*   rows          = (const int*)d_in[1];
    const int*   cols          = (const int*)d_in[2];
    const float* edge_vals     = (const float*)d_in[3];
    const int*   pairs         = (const int*)d_in[4];
    const float* node_emb      = (const float*)d_in[5];
    const float* type_emb      = (const float*)d_in[6];
    const float* W1            = (const float*)d_in[7];
    const float* b1            = (const float*)d_in[8];
    const float* W2            = (const float*)d_in[9];
    const float* b2            = (const float*)d_in[10];
    const float* Wp1           = (const float*)d_in[11];
    const float* bp1           = (const float*)d_in[12];
    const float* Wp2           = (const float*)d_in[13];
    const float* bp2           = (const float*)d_in[14];
    float* out = (float*)d_out;

    const size_t MB = 1ull << 20;
    char* ws = (char*)d_ws;
    int*      rp   = (int*)(ws);
    _Float16* xa   = (_Float16*)(ws + 4 * MB);     // [100K,128] 25.6 MB
    _Float16* xb   = (_Float16*)(ws + 32 * MB);    // [100K,128] 25.6 MB
    _Float16* s1   = (_Float16*)(ws + 60 * MB);    // [100K,256] 51.2 MB
    _Float16* h16  = (_Float16*)(ws + 112 * MB);   // [100K,256] 51.2 MB
    _Float16* g16  = (_Float16*)(ws + 164 * MB);   // [100K,128] 25.6 MB
    _Float16* z16  = (_Float16*)(ws + 190 * MB);   // [100K,128] 25.6 MB
    _Float16* W1t  = (_Float16*)(ws + 216 * MB);
    _Float16* W2t  = (_Float16*)(ws + 217 * MB);
    _Float16* Wp1t = (_Float16*)(ws + 218 * MB);

    // prep
    build_rowptr_k<<<(N_NODES + 256) / 256, 256, 0, stream>>>(rows, rp, N_NODES, N_EDGES);
    build_x16_k<<<(N_NODES * 64 + 255) / 256, 256, 0, stream>>>(node_emb, type_emb,
                                                                node_type_ids, xa, xb);
    transpose_w_k<<<(HIDDEN * HIDDEN + 255) / 256, 256, 0, stream>>>(W1, W1t, HIDDEN, HIDDEN);
    transpose_w_k<<<(HIDDEN * EMBED + 255) / 256, 256, 0, stream>>>(W2, W2t, HIDDEN, EMBED);
    transpose_wp1_k<<<EMBED, 3 * EMBED, 0, stream>>>(Wp1, Wp1t);

    // s1 = spmm(x) in two half-table passes (sequential launches keep the
    // active gather table at 25.6 MB)
    spmm128_k<false><<<N_NODES / 4, 256, 0, stream>>>(rp, cols, edge_vals, xa,
                                                      nullptr, s1, HIDDEN, 0);
    spmm128_k<false><<<N_NODES / 4, 256, 0, stream>>>(rp, cols, edge_vals, xb,
                                                      nullptr, s1, HIDDEN, 128);

    // h = relu(s1 @ W1 + b1)
    {
        dim3 grid((N_NODES + 127) / 128, HIDDEN / 128);
        gemm16_k<true, true><<<grid, 256, 0, stream>>>(s1, W1t, b1, h16, N_NODES, HIDDEN);
    }

    // g = h @ W2   (z = spmm(g) + b2 by linearity)
    {
        dim3 grid((N_NODES + 127) / 128, EMBED / 128);
        gemm16_k<false, false><<<grid, 256, 0, stream>>>(h16, W2t, nullptr, g16, N_NODES, EMBED);
    }

    // z16 = spmm(g) + b2
    spmm128_k<true><<<N_NODES / 4, 256, 0, stream>>>(rp, cols, edge_vals, g16,
                                                     b2, z16, EMBED, 0);

    // scorer
    scorer_mfma_k<<<(N_PAIRS + 127) / 128, 256, 0, stream>>>(z16, pairs, Wp1t, bp1,
                                                             Wp2, bp2, out, N_PAIRS);
}